// Round 6
// baseline (282.152 us; speedup 1.0000x reference)
//
#include <hip/hip_runtime.h>
#include <hip/hip_bf16.h>

#define NN 50000
#define NR 8
#define NE 800000

typedef short bf16x8 __attribute__((ext_vector_type(8)));
typedef float f32x4  __attribute__((ext_vector_type(4)));

// ---------- helpers ----------
__device__ __forceinline__ unsigned fkey(float f) {
    unsigned b = __float_as_uint(f);
    return (b & 0x80000000u) ? ~b : (b | 0x80000000u);
}
__device__ __forceinline__ float funkey(unsigned k) {
    unsigned b = (k & 0x80000000u) ? (k ^ 0x80000000u) : ~k;
    return __uint_as_float(b);
}
__device__ __forceinline__ unsigned short f2bf(float f) {
    unsigned u = __float_as_uint(f);
    unsigned r = (u + 0x7FFFu + ((u >> 16) & 1u)) >> 16;
    return (unsigned short)r;
}
__device__ __forceinline__ float bf2f(unsigned short b) {
    return __uint_as_float(((unsigned)b) << 16);
}

// ---------- P0: x->bf16 tables, W->Wt[r][o][k] bf16, bias sums ----------
__global__ __launch_bounds__(256) void prep_kernel(
    const float* __restrict__ feat, const float* __restrict__ nq,
    const float* __restrict__ WS, const float* __restrict__ WQ,
    const float* __restrict__ bS, const float* __restrict__ bQ,
    unsigned short* __restrict__ xS, unsigned short* __restrict__ xQ,
    unsigned short* __restrict__ WtS, unsigned short* __restrict__ WtQ,
    float* __restrict__ bSQ)
{
    const int idx = blockIdx.x * 256 + threadIdx.x;
    const int NX = NN * 64 / 4;                      // 800000 float4s per table
    if (idx < NX) {
        const float4 v = reinterpret_cast<const float4*>(feat)[idx];
        ushort4 p; p.x = f2bf(v.x); p.y = f2bf(v.y); p.z = f2bf(v.z); p.w = f2bf(v.w);
        reinterpret_cast<ushort4*>(xS)[idx] = p;
    } else if (idx < 2 * NX) {
        const float4 v = reinterpret_cast<const float4*>(nq)[idx - NX];
        ushort4 p; p.x = f2bf(v.x); p.y = f2bf(v.y); p.z = f2bf(v.z); p.w = f2bf(v.w);
        reinterpret_cast<ushort4*>(xQ)[idx - NX] = p;
    } else {
        int i = idx - 2 * NX;
        if (i < 32768) {
            const int r = i >> 12, rem = i & 4095, o = rem >> 6, k = rem & 63;
            WtS[i] = f2bf(WS[(size_t)r * 4096 + k * 64 + o]);
        } else if (i < 65536) {
            i -= 32768;
            const int r = i >> 12, rem = i & 4095, o = rem >> 6, k = rem & 63;
            WtQ[i] = f2bf(WQ[(size_t)r * 4096 + k * 64 + o]);
        } else if (i < 65536 + 512) {
            const int j = i - 65536;
            bSQ[j] = bS[j] + bQ[j];
        }
    }
}

// ---------- combined histogram: per-dst counts + per-relation counts ----------
__global__ __launch_bounds__(256) void hist_kernel(
    const int* __restrict__ dst, const int* __restrict__ rt,
    int* __restrict__ cnt, int* __restrict__ cnt_r)
{
    __shared__ int h[8];
    const int t = threadIdx.x;
    if (t < 8) h[t] = 0;
    __syncthreads();
    const int e = blockIdx.x * 256 + t;
    if (e < NE) {
        atomicAdd(&cnt[dst[e]], 1);
        atomicAdd(&h[rt[e]], 1);
    }
    __syncthreads();
    if (t < 8 && h[t]) atomicAdd(&cnt_r[t], h[t]);
}

// ---------- dst-CSR scan ----------
__global__ __launch_bounds__(256) void scan1_kernel(
    const int* __restrict__ cnt, int* __restrict__ offs, int* __restrict__ partial)
{
    __shared__ int s[256];
    const int t = threadIdx.x, i = blockIdx.x * 256 + t;
    const int v = (i < NN) ? cnt[i] : 0;
    s[t] = v;
    __syncthreads();
    #pragma unroll
    for (int off = 1; off < 256; off <<= 1) {
        const int x = (t >= off) ? s[t - off] : 0;
        __syncthreads();
        s[t] += x;
        __syncthreads();
    }
    if (i < NN) offs[i] = s[t] - v;
    if (t == 255) partial[blockIdx.x] = s[255];
}

__global__ __launch_bounds__(256) void scan2_kernel(int* __restrict__ partial, const int nblk)
{
    __shared__ int s[256];
    const int t = threadIdx.x;
    const int v = (t < nblk) ? partial[t] : 0;
    s[t] = v;
    __syncthreads();
    #pragma unroll
    for (int off = 1; off < 256; off <<= 1) {
        const int x = (t >= off) ? s[t - off] : 0;
        __syncthreads();
        s[t] += x;
        __syncthreads();
    }
    if (t < nblk) partial[t] = s[t] - v;
}

__global__ __launch_bounds__(256) void scan3_kernel(
    int* __restrict__ offs, const int* __restrict__ partial)
{
    const int i = blockIdx.x * 256 + threadIdx.x;
    if (i < NN) offs[i] += partial[blockIdx.x];
    if (i == 0) offs[NN] = NE;
}

// ---------- relation-bucket offsets (padded to multiples of 16) ----------
__global__ void scanr_kernel(const int* __restrict__ cnt_r,
                             int* __restrict__ off_pad, int* __restrict__ cursor_r)
{
    if (threadIdx.x == 0) {
        int acc = 0;
        for (int r = 0; r < NR; ++r) {
            off_pad[r] = acc;
            cursor_r[r] = acc;
            acc += (cnt_r[r] + 15) & ~15;
        }
        off_pad[NR] = acc;
    }
}

// ---------- relation-bucket fill (LDS-aggregated counting sort) ----------
__global__ __launch_bounds__(256) void fillr_kernel(
    const int* __restrict__ rt, int* __restrict__ cursor_r, int* __restrict__ re)
{
    __shared__ int lh[8], base[8];
    const int t = threadIdx.x;
    if (t < 8) lh[t] = 0;
    __syncthreads();
    const int e = blockIdx.x * 256 + t;
    int r = 0, rank = 0;
    if (e < NE) {
        r = rt[e];
        rank = atomicAdd(&lh[r], 1);
    }
    __syncthreads();
    if (t < 8 && lh[t]) base[t] = atomicAdd(&cursor_r[t], lh[t]);
    __syncthreads();
    if (e < NE) re[base[r] + rank] = e;
}

// ---------- K2: per-edge MFMA logits + fused CSR fill ----------
// One wave = 16 edges of a single relation bucket.
// D[o][edge] = sum_k WtS[r][o][k]*xS[src][k] + WtQ[r][o][k]*xQ[nid][k]
// then p_h = sum_o LRelu(D+b)*attn ; scatter {src, p0, p1} to CSR slot.
__global__ __launch_bounds__(256) void logits_kernel(
    const unsigned short* __restrict__ xS, const unsigned short* __restrict__ xQ,
    const unsigned short* __restrict__ WtS, const unsigned short* __restrict__ WtQ,
    const float* __restrict__ bSQ, const float* __restrict__ attn,
    const int* __restrict__ src, const int* __restrict__ dst, const int* __restrict__ nid,
    const int* __restrict__ re, const int* __restrict__ off_pad,
    const int* __restrict__ offs, int* __restrict__ cursor, float4* __restrict__ perm)
{
    const int wid = (blockIdx.x * 256 + threadIdx.x) >> 6;
    const int slot0 = wid * 16;
    int r = 0;
    #pragma unroll
    for (int i = 1; i <= 8; ++i) r += (slot0 >= off_pad[i]);
    if (r >= 8) return;                       // past the end

    const int lane = threadIdx.x & 63;
    const int l15  = lane & 15;
    const int g    = lane >> 4;

    const int eid = re[slot0 + l15];
    const bool valid = eid >= 0;
    const int s = valid ? src[eid] : 0;
    const int q = valid ? nid[eid] : 0;

    bf16x8 xf[2], qf[2];
    #pragma unroll
    for (int kf = 0; kf < 2; ++kf) {
        xf[kf] = *reinterpret_cast<const bf16x8*>(xS + (size_t)s * 64 + kf * 32 + g * 8);
        qf[kf] = *reinterpret_cast<const bf16x8*>(xQ + (size_t)q * 64 + kf * 32 + g * 8);
    }

    float p0 = 0.f, p1 = 0.f;
    #pragma unroll
    for (int ot = 0; ot < 4; ++ot) {
        const size_t wb = ((size_t)r * 64 + ot * 16 + l15) * 64;
        const bf16x8 wS0 = *reinterpret_cast<const bf16x8*>(WtS + wb + g * 8);
        const bf16x8 wS1 = *reinterpret_cast<const bf16x8*>(WtS + wb + 32 + g * 8);
        const bf16x8 wQ0 = *reinterpret_cast<const bf16x8*>(WtQ + wb + g * 8);
        const bf16x8 wQ1 = *reinterpret_cast<const bf16x8*>(WtQ + wb + 32 + g * 8);
        f32x4 acc = (f32x4){0.f, 0.f, 0.f, 0.f};
        acc = __builtin_amdgcn_mfma_f32_16x16x32_bf16(wS0, xf[0], acc, 0, 0, 0);
        acc = __builtin_amdgcn_mfma_f32_16x16x32_bf16(wS1, xf[1], acc, 0, 0, 0);
        acc = __builtin_amdgcn_mfma_f32_16x16x32_bf16(wQ0, qf[0], acc, 0, 0, 0);
        acc = __builtin_amdgcn_mfma_f32_16x16x32_bf16(wQ1, qf[1], acc, 0, 0, 0);
        // rows o = ot*16 + g*4 + j, col = edge (l15)
        const f32x4 bv = *reinterpret_cast<const f32x4*>(bSQ + r * 64 + ot * 16 + g * 4);
        const f32x4 av = *reinterpret_cast<const f32x4*>(attn + r * 64 + ot * 16 + g * 4);
        float part = 0.f;
        #pragma unroll
        for (int j = 0; j < 4; ++j) {
            float v = acc[j] + bv[j];
            v = v > 0.f ? v : 0.2f * v;
            part += v * av[j];
        }
        if (ot < 2) p0 += part; else p1 += part;
    }
    p0 += __shfl_xor(p0, 16); p0 += __shfl_xor(p0, 32);
    p1 += __shfl_xor(p1, 16); p1 += __shfl_xor(p1, 32);

    if (g == 0 && valid) {
        const int dn = dst[eid];
        const int j = offs[dn] + atomicAdd(&cursor[dn], 1);
        perm[j] = make_float4(__int_as_float(s), p0, p1, 0.f);
    }
}

// ---------- K4: per-node softmax + aggregation (2 edges/iter, half-wave each) ----------
__global__ __launch_bounds__(256) void aggregate_kernel(
    const float* __restrict__ feat, const int* __restrict__ offs,
    const float4* __restrict__ perm, float* __restrict__ out)
{
    __shared__ float2 ebuf[4][64];
    __shared__ int    sbuf[4][64];
    const int wv = threadIdx.x >> 6;
    const int n = blockIdx.x * 4 + wv;
    if (n >= NN) return;
    const int lane = threadIdx.x & 63;
    const int h2 = lane >> 5;        // which edge of the pair
    const int dp = lane & 31;        // d-pair: covers d = 2dp, 2dp+1
    const int s0 = offs[n], s1 = offs[n + 1];
    float a00 = 0.f, a01 = 0.f, a10 = 0.f, a11 = 0.f;   // [head][even/odd d]
    float d0s = 0.f, d1s = 0.f;
    if (s1 > s0) {
        float m0 = -1e30f, m1 = -1e30f;
        for (int j = s0 + lane; j < s1; j += 64) {
            const float4 p = perm[j];
            m0 = fmaxf(m0, p.y); m1 = fmaxf(m1, p.z);
        }
        #pragma unroll
        for (int m = 32; m; m >>= 1) {
            m0 = fmaxf(m0, __shfl_xor(m0, m));
            m1 = fmaxf(m1, __shfl_xor(m1, m));
        }
        for (int c = s0; c < s1; c += 64) {
            const int cnt = min(64, s1 - c);
            if (lane < cnt) {
                const float4 p = perm[c + lane];
                const float e0 = __expf(p.y - m0);
                const float e1 = __expf(p.z - m1);
                d0s += e0; d1s += e1;
                ebuf[wv][lane] = make_float2(e0, e1);
                sbuf[wv][lane] = (int)__float_as_uint(p.x);
            } else if (lane == cnt) {            // zero-weight pad for odd tails
                ebuf[wv][lane] = make_float2(0.f, 0.f);
                sbuf[wv][lane] = 0;
            }
            const int cp = cnt + (cnt & 1);
            #pragma unroll 4
            for (int k = 0; k < cp; k += 2) {
                const int ei = k + h2;
                const int sA = sbuf[wv][ei];
                const float2 w = ebuf[wv][ei];
                const float2 f = *reinterpret_cast<const float2*>(
                    &feat[(size_t)sA * 64 + dp * 2]);
                a00 += f.x * w.x; a01 += f.y * w.x;
                a10 += f.x * w.y; a11 += f.y * w.y;
            }
        }
        #pragma unroll
        for (int m = 32; m; m >>= 1) {
            d0s += __shfl_xor(d0s, m);
            d1s += __shfl_xor(d1s, m);
        }
        a00 += __shfl_xor(a00, 32); a01 += __shfl_xor(a01, 32);
        a10 += __shfl_xor(a10, 32); a11 += __shfl_xor(a11, 32);
        const float r0 = 1.f / d0s, r1 = 1.f / d1s;
        a00 *= r0; a01 *= r0; a10 *= r1; a11 *= r1;
    }
    if (h2 == 0)
        *reinterpret_cast<float2*>(&out[(size_t)n * 128 + dp * 2])      = make_float2(a00, a01);
    else
        *reinterpret_cast<float2*>(&out[(size_t)n * 128 + 64 + dp * 2]) = make_float2(a10, a11);
}

// ---------- minimal-workspace fallback: direct logits + atomic scatter ----------
__global__ __launch_bounds__(256) void logits_direct_kernel(
    const float* __restrict__ feat, const float* __restrict__ nq,
    const int* __restrict__ src, const int* __restrict__ dst,
    const int* __restrict__ rt, const int* __restrict__ nid,
    const float* __restrict__ fc_src, const float* __restrict__ fc_src_b,
    const float* __restrict__ fc_qual, const float* __restrict__ fc_qual_b,
    const float* __restrict__ attn,
    float* __restrict__ e_buf, unsigned* __restrict__ emax)
{
    __shared__ float Ws[64][64];
    __shared__ float Wq[64][64];
    __shared__ float bl[64];
    __shared__ float al[64];
    const int r = blockIdx.y;
    const int t = threadIdx.x;
    for (int i = t; i < 4096; i += 256) {
        ((float*)Ws)[i] = fc_src[(size_t)r * 4096 + i];
        ((float*)Wq)[i] = fc_qual[(size_t)r * 4096 + i];
    }
    if (t < 64) {
        bl[t] = fc_src_b[r * 64 + t] + fc_qual_b[r * 64 + t];
        al[t] = attn[r * 64 + t];
    }
    __syncthreads();

    const int lane = t & 63;
    const int wid = blockIdx.x * 4 + (t >> 6);
    const int nw = gridDim.x * 4;
    for (int e = wid; e < NE; e += nw) {
        if (rt[e] != r) continue;
        const int s = src[e], q = nid[e];
        float fv = feat[(size_t)s * 64 + lane];
        float qv = nq[(size_t)q * 64 + lane];
        float acc = bl[lane];
        for (int k = 0; k < 64; ++k) {
            acc += __shfl(fv, k) * Ws[k][lane];
            acc += __shfl(qv, k) * Wq[k][lane];
        }
        acc = acc > 0.f ? acc : 0.2f * acc;
        float p = acc * al[lane];
        #pragma unroll
        for (int m = 1; m < 32; m <<= 1) p += __shfl_xor(p, m);
        if ((lane & 31) == 0) {
            int h = lane >> 5;
            e_buf[(size_t)e * 2 + h] = p;
            atomicMax(&emax[(size_t)dst[e] * 2 + h], fkey(p));
        }
    }
}

__global__ __launch_bounds__(256) void expdenom_kernel(
    const int* __restrict__ dst, float* __restrict__ e_buf,
    const unsigned* __restrict__ emax, float* __restrict__ denom)
{
    const int i = blockIdx.x * 256 + threadIdx.x;
    if (i >= NE * 2) return;
    const int e = i >> 1, h = i & 1;
    const int dn = dst[e];
    const float m = funkey(emax[(size_t)dn * 2 + h]);
    const float ex = __expf(e_buf[i] - m);
    e_buf[i] = ex;
    unsafeAtomicAdd(&denom[(size_t)dn * 2 + h], ex);
}

__global__ __launch_bounds__(256) void scatter_kernel(
    const float* __restrict__ feat, const int* __restrict__ src, const int* __restrict__ dst,
    const float* __restrict__ ex, const float* __restrict__ denom, float* __restrict__ out)
{
    const int e = blockIdx.x * 4 + (threadIdx.x >> 6);
    if (e >= NE) return;
    const int lane = threadIdx.x & 63;
    const int s = src[e], dn = dst[e];
    const float f = feat[(size_t)s * 64 + lane];
    const float a0 = ex[(size_t)e * 2]     / denom[(size_t)dn * 2];
    const float a1 = ex[(size_t)e * 2 + 1] / denom[(size_t)dn * 2 + 1];
    unsafeAtomicAdd(&out[(size_t)dn * 128 + lane],      f * a0);
    unsafeAtomicAdd(&out[(size_t)dn * 128 + 64 + lane], f * a1);
}

extern "C" void kernel_launch(void* const* d_in, const int* in_sizes, int n_in,
                              void* d_out, int out_size, void* d_ws, size_t ws_size,
                              hipStream_t stream)
{
    const float* feat      = (const float*)d_in[0];
    const int*   src       = (const int*)d_in[1];
    const int*   dst       = (const int*)d_in[2];
    const int*   rt        = (const int*)d_in[3];
    const int*   nid       = (const int*)d_in[4];
    const float* fc_src    = (const float*)d_in[5];
    const float* fc_src_b  = (const float*)d_in[6];
    const float* nq        = (const float*)d_in[7];
    const float* fc_qual   = (const float*)d_in[8];
    const float* fc_qual_b = (const float*)d_in[9];
    const float* attn      = (const float*)d_in[10];
    float* out = (float*)d_out;

    char* ws = (char*)d_ws;

    // ---- layout (no aliasing; ~32 MB total) ----
    int*    cnt      = (int*)ws;                            // NN           @0
    int*    cursor   = (int*)(ws + 262144);                 // NN
    int*    offs     = (int*)(ws + 524288);                 // NN+1
    int*    partial  = (int*)(ws + 786432);                 // 256
    int*    cnt_r    = (int*)(ws + 800000);                 // 8
    int*    off_pad  = (int*)(ws + 800064);                 // 9
    int*    cursor_r = (int*)(ws + 800128);                 // 8
    int*    re       = (int*)(ws + 1048576);                // NE+128
    float4* perm     = (float4*)(ws + 5242880);             // NE float4 (12.8MB)
    unsigned short* xS  = (unsigned short*)(ws + 18874368); // 6.4MB
    unsigned short* xQ  = (unsigned short*)(ws + 25274368); // 6.4MB
    unsigned short* WtS = (unsigned short*)(ws + 31674368); // 64KB
    unsigned short* WtQ = (unsigned short*)(ws + 31739904); // 64KB
    float*          bSQ = (float*)(ws + 31805440);          // 2KB
    const size_t need = 31807488;

    if (ws_size >= need) {
        prep_kernel<<<(2 * (NN * 64 / 4) + 65536 + 512 + 255) / 256, 256, 0, stream>>>(
            feat, nq, fc_src, fc_qual, fc_src_b, fc_qual_b, xS, xQ, WtS, WtQ, bSQ);

        hipMemsetAsync(ws, 0, 524288, stream);              // cnt + cursor
        hipMemsetAsync(ws + 800000, 0, 256, stream);        // cnt_r/off_pad/cursor_r
        hipMemsetAsync(re, 0xFF, (size_t)(NE + 128) * 4, stream);

        hist_kernel<<<(NE + 255) / 256, 256, 0, stream>>>(dst, rt, cnt, cnt_r);
        const int nblk = (NN + 255) / 256;
        scan1_kernel<<<nblk, 256, 0, stream>>>(cnt, offs, partial);
        scan2_kernel<<<1, 256, 0, stream>>>(partial, nblk);
        scan3_kernel<<<nblk, 256, 0, stream>>>(offs, partial);
        scanr_kernel<<<1, 64, 0, stream>>>(cnt_r, off_pad, cursor_r);
        fillr_kernel<<<(NE + 255) / 256, 256, 0, stream>>>(rt, cursor_r, re);

        logits_kernel<<<(NE + 128 + 63) / 64, 256, 0, stream>>>(
            xS, xQ, WtS, WtQ, bSQ, attn, src, dst, nid,
            re, off_pad, offs, cursor, perm);
        aggregate_kernel<<<(NN + 3) / 4, 256, 0, stream>>>(feat, offs, perm, out);
    } else {
        // minimal-workspace fallback (atomic path)
        float*    e_buf = (float*)ws;
        unsigned* emax  = (unsigned*)(ws + (size_t)NE * 2 * 4);
        float*    denom = (float*)(ws + (size_t)NE * 2 * 4 + (size_t)NN * 2 * 4);
        hipMemsetAsync(out, 0, (size_t)out_size * sizeof(float), stream);
        hipMemsetAsync(emax, 0, (size_t)NN * 2 * 4 * 2, stream);
        dim3 g(256, NR);
        logits_direct_kernel<<<g, 256, 0, stream>>>(
            feat, nq, src, dst, rt, nid, fc_src, fc_src_b, fc_qual, fc_qual_b,
            attn, e_buf, emax);
        expdenom_kernel<<<(NE * 2 + 255) / 256, 256, 0, stream>>>(dst, e_buf, emax, denom);
        scatter_kernel<<<(NE + 3) / 4, 256, 0, stream>>>(feat, src, dst, e_buf, denom, out);
    }
}

// Round 7
// 240.871 us; speedup vs baseline: 1.1714x; 1.1714x over previous
//
#include <hip/hip_runtime.h>
#include <hip/hip_bf16.h>

#define NN 50000
#define NR 8
#define NE 800000

typedef short bf16x8 __attribute__((ext_vector_type(8)));
typedef float f32x4  __attribute__((ext_vector_type(4)));

// ---------- helpers ----------
__device__ __forceinline__ unsigned fkey(float f) {
    unsigned b = __float_as_uint(f);
    return (b & 0x80000000u) ? ~b : (b | 0x80000000u);
}
__device__ __forceinline__ float funkey(unsigned k) {
    unsigned b = (k & 0x80000000u) ? (k ^ 0x80000000u) : ~k;
    return __uint_as_float(b);
}
__device__ __forceinline__ unsigned short f2bf(float f) {
    unsigned u = __float_as_uint(f);
    unsigned r = (u + 0x7FFFu + ((u >> 16) & 1u)) >> 16;
    return (unsigned short)r;
}
__device__ __forceinline__ float bf2f(unsigned short b) {
    return __uint_as_float(((unsigned)b) << 16);
}

// ---------- P0: x->bf16 tables, W->Wt[r][o][k] bf16, bias sums ----------
__global__ __launch_bounds__(256) void prep_kernel(
    const float* __restrict__ feat, const float* __restrict__ nq,
    const float* __restrict__ WS, const float* __restrict__ WQ,
    const float* __restrict__ bS, const float* __restrict__ bQ,
    unsigned short* __restrict__ xS, unsigned short* __restrict__ xQ,
    unsigned short* __restrict__ WtS, unsigned short* __restrict__ WtQ,
    float* __restrict__ bSQ)
{
    const int idx = blockIdx.x * 256 + threadIdx.x;
    const int NX = NN * 64 / 4;                      // 800000 float4s per table
    if (idx < NX) {
        const float4 v = reinterpret_cast<const float4*>(feat)[idx];
        ushort4 p; p.x = f2bf(v.x); p.y = f2bf(v.y); p.z = f2bf(v.z); p.w = f2bf(v.w);
        reinterpret_cast<ushort4*>(xS)[idx] = p;
    } else if (idx < 2 * NX) {
        const float4 v = reinterpret_cast<const float4*>(nq)[idx - NX];
        ushort4 p; p.x = f2bf(v.x); p.y = f2bf(v.y); p.z = f2bf(v.z); p.w = f2bf(v.w);
        reinterpret_cast<ushort4*>(xQ)[idx - NX] = p;
    } else {
        int i = idx - 2 * NX;
        if (i < 32768) {
            const int r = i >> 12, rem = i & 4095, o = rem >> 6, k = rem & 63;
            WtS[i] = f2bf(WS[(size_t)r * 4096 + k * 64 + o]);
        } else if (i < 65536) {
            i -= 32768;
            const int r = i >> 12, rem = i & 4095, o = rem >> 6, k = rem & 63;
            WtQ[i] = f2bf(WQ[(size_t)r * 4096 + k * 64 + o]);
        } else if (i < 65536 + 512) {
            const int j = i - 65536;
            bSQ[j] = bS[j] + bQ[j];
        }
    }
}

// ---------- combined histogram: per-dst counts + per-relation counts ----------
__global__ __launch_bounds__(256) void hist_kernel(
    const int* __restrict__ dst, const int* __restrict__ rt,
    int* __restrict__ cnt, int* __restrict__ cnt_r)
{
    __shared__ int h[8];
    const int t = threadIdx.x;
    if (t < 8) h[t] = 0;
    __syncthreads();
    const int e = blockIdx.x * 256 + t;
    if (e < NE) {
        atomicAdd(&cnt[dst[e]], 1);
        atomicAdd(&h[rt[e]], 1);
    }
    __syncthreads();
    if (t < 8 && h[t]) atomicAdd(&cnt_r[t], h[t]);
}

// ---------- dst-CSR scan ----------
__global__ __launch_bounds__(256) void scan1_kernel(
    const int* __restrict__ cnt, int* __restrict__ offs, int* __restrict__ partial)
{
    __shared__ int s[256];
    const int t = threadIdx.x, i = blockIdx.x * 256 + t;
    const int v = (i < NN) ? cnt[i] : 0;
    s[t] = v;
    __syncthreads();
    #pragma unroll
    for (int off = 1; off < 256; off <<= 1) {
        const int x = (t >= off) ? s[t - off] : 0;
        __syncthreads();
        s[t] += x;
        __syncthreads();
    }
    if (i < NN) offs[i] = s[t] - v;
    if (t == 255) partial[blockIdx.x] = s[255];
}

__global__ __launch_bounds__(256) void scan2_kernel(int* __restrict__ partial, const int nblk)
{
    __shared__ int s[256];
    const int t = threadIdx.x;
    const int v = (t < nblk) ? partial[t] : 0;
    s[t] = v;
    __syncthreads();
    #pragma unroll
    for (int off = 1; off < 256; off <<= 1) {
        const int x = (t >= off) ? s[t - off] : 0;
        __syncthreads();
        s[t] += x;
        __syncthreads();
    }
    if (t < nblk) partial[t] = s[t] - v;
}

__global__ __launch_bounds__(256) void scan3_kernel(
    int* __restrict__ offs, const int* __restrict__ partial)
{
    const int i = blockIdx.x * 256 + threadIdx.x;
    if (i < NN) offs[i] += partial[blockIdx.x];
    if (i == 0) offs[NN] = NE;
}

// ---------- relation-bucket offsets (padded to multiples of 64) ----------
__global__ void scanr_kernel(const int* __restrict__ cnt_r,
                             int* __restrict__ off_pad, int* __restrict__ cursor_r)
{
    if (threadIdx.x == 0) {
        int acc = 0;
        for (int r = 0; r < NR; ++r) {
            off_pad[r] = acc;
            cursor_r[r] = acc;
            acc += (cnt_r[r] + 63) & ~63;
        }
        off_pad[NR] = acc;
    }
}

// ---------- relation-bucket fill (LDS-aggregated counting sort) ----------
__global__ __launch_bounds__(256) void fillr_kernel(
    const int* __restrict__ rt, int* __restrict__ cursor_r, int* __restrict__ re)
{
    __shared__ int lh[8], base[8];
    const int t = threadIdx.x;
    if (t < 8) lh[t] = 0;
    __syncthreads();
    const int e = blockIdx.x * 256 + t;
    int r = 0, rank = 0;
    if (e < NE) {
        r = rt[e];
        rank = atomicAdd(&lh[r], 1);
    }
    __syncthreads();
    if (t < 8 && lh[t]) base[t] = atomicAdd(&cursor_r[t], lh[t]);
    __syncthreads();
    if (e < NE) re[base[r] + rank] = e;
}

// ---------- K2: batched per-edge MFMA logits + fused CSR fill ----------
// One wave = 64 edges (4 sub-batches of 16) of one relation bucket.
// All gathers issued up-front (16 x 16B per lane in flight); W/bias/attn hoisted.
__global__ __launch_bounds__(256) void logits_kernel(
    const unsigned short* __restrict__ xS, const unsigned short* __restrict__ xQ,
    const unsigned short* __restrict__ WtS, const unsigned short* __restrict__ WtQ,
    const float* __restrict__ bSQ, const float* __restrict__ attn,
    const int* __restrict__ src, const int* __restrict__ dst, const int* __restrict__ nid,
    const int* __restrict__ re, const int* __restrict__ off_pad,
    const int* __restrict__ offs, int* __restrict__ cursor, float4* __restrict__ perm)
{
    const int wid = (blockIdx.x * 256 + threadIdx.x) >> 6;
    const int slot0 = wid * 64;
    int r = 0;
    #pragma unroll
    for (int i = 1; i <= 8; ++i) r += (slot0 >= off_pad[i]);
    if (r >= 8) return;                       // past the end

    const int lane = threadIdx.x & 63;
    const int l15  = lane & 15;
    const int g    = lane >> 4;

    // ---- hoisted per-relation operands ----
    bf16x8 wS0[4], wS1[4], wQ0[4], wQ1[4];
    f32x4  bv[4], av[4];
    #pragma unroll
    for (int ot = 0; ot < 4; ++ot) {
        const size_t wb = ((size_t)r * 64 + ot * 16 + l15) * 64 + g * 8;
        wS0[ot] = *reinterpret_cast<const bf16x8*>(WtS + wb);
        wS1[ot] = *reinterpret_cast<const bf16x8*>(WtS + wb + 32);
        wQ0[ot] = *reinterpret_cast<const bf16x8*>(WtQ + wb);
        wQ1[ot] = *reinterpret_cast<const bf16x8*>(WtQ + wb + 32);
        bv[ot]  = *reinterpret_cast<const f32x4*>(bSQ  + r * 64 + ot * 16 + g * 4);
        av[ot]  = *reinterpret_cast<const f32x4*>(attn + r * 64 + ot * 16 + g * 4);
    }

    // ---- all 4 sub-batches: eid -> src/nid -> x/q fragments, issued up-front ----
    int eid[4], sv[4], qv[4];
    #pragma unroll
    for (int b = 0; b < 4; ++b) eid[b] = re[slot0 + b * 16 + l15];
    #pragma unroll
    for (int b = 0; b < 4; ++b) {
        sv[b] = (eid[b] >= 0) ? src[eid[b]] : 0;
        qv[b] = (eid[b] >= 0) ? nid[eid[b]] : 0;
    }
    bf16x8 xf[4][2], qf[4][2];
    #pragma unroll
    for (int b = 0; b < 4; ++b) {
        xf[b][0] = *reinterpret_cast<const bf16x8*>(xS + (size_t)sv[b] * 64 + g * 8);
        xf[b][1] = *reinterpret_cast<const bf16x8*>(xS + (size_t)sv[b] * 64 + 32 + g * 8);
        qf[b][0] = *reinterpret_cast<const bf16x8*>(xQ + (size_t)qv[b] * 64 + g * 8);
        qf[b][1] = *reinterpret_cast<const bf16x8*>(xQ + (size_t)qv[b] * 64 + 32 + g * 8);
    }

    // ---- compute + scatter per sub-batch ----
    #pragma unroll
    for (int b = 0; b < 4; ++b) {
        float p0 = 0.f, p1 = 0.f;
        #pragma unroll
        for (int ot = 0; ot < 4; ++ot) {
            f32x4 acc = (f32x4){0.f, 0.f, 0.f, 0.f};
            acc = __builtin_amdgcn_mfma_f32_16x16x32_bf16(wS0[ot], xf[b][0], acc, 0, 0, 0);
            acc = __builtin_amdgcn_mfma_f32_16x16x32_bf16(wS1[ot], xf[b][1], acc, 0, 0, 0);
            acc = __builtin_amdgcn_mfma_f32_16x16x32_bf16(wQ0[ot], qf[b][0], acc, 0, 0, 0);
            acc = __builtin_amdgcn_mfma_f32_16x16x32_bf16(wQ1[ot], qf[b][1], acc, 0, 0, 0);
            float part = 0.f;
            #pragma unroll
            for (int j = 0; j < 4; ++j) {
                float v = acc[j] + bv[ot][j];
                v = v > 0.f ? v : 0.2f * v;
                part += v * av[ot][j];
            }
            if (ot < 2) p0 += part; else p1 += part;
        }
        p0 += __shfl_xor(p0, 16); p0 += __shfl_xor(p0, 32);
        p1 += __shfl_xor(p1, 16); p1 += __shfl_xor(p1, 32);
        if (g == 0 && eid[b] >= 0) {
            const int dn = dst[eid[b]];
            const int j = offs[dn] + atomicAdd(&cursor[dn], 1);
            perm[j] = make_float4(__int_as_float(sv[b]), p0, p1, 0.f);
        }
    }
}

// ---------- K4: per-node softmax + aggregation (2 edges/iter, half-wave each) ----------
__global__ __launch_bounds__(256) void aggregate_kernel(
    const float* __restrict__ feat, const int* __restrict__ offs,
    const float4* __restrict__ perm, float* __restrict__ out)
{
    __shared__ float2 ebuf[4][64];
    __shared__ int    sbuf[4][64];
    const int wv = threadIdx.x >> 6;
    const int n = blockIdx.x * 4 + wv;
    if (n >= NN) return;
    const int lane = threadIdx.x & 63;
    const int h2 = lane >> 5;        // which edge of the pair
    const int dp = lane & 31;        // d-pair: covers d = 2dp, 2dp+1
    const int s0 = offs[n], s1 = offs[n + 1];
    float a00 = 0.f, a01 = 0.f, a10 = 0.f, a11 = 0.f;   // [head][even/odd d]
    float d0s = 0.f, d1s = 0.f;
    if (s1 > s0) {
        float m0 = -1e30f, m1 = -1e30f;
        for (int j = s0 + lane; j < s1; j += 64) {
            const float4 p = perm[j];
            m0 = fmaxf(m0, p.y); m1 = fmaxf(m1, p.z);
        }
        #pragma unroll
        for (int m = 32; m; m >>= 1) {
            m0 = fmaxf(m0, __shfl_xor(m0, m));
            m1 = fmaxf(m1, __shfl_xor(m1, m));
        }
        for (int c = s0; c < s1; c += 64) {
            const int cnt = min(64, s1 - c);
            if (lane < cnt) {
                const float4 p = perm[c + lane];
                const float e0 = __expf(p.y - m0);
                const float e1 = __expf(p.z - m1);
                d0s += e0; d1s += e1;
                ebuf[wv][lane] = make_float2(e0, e1);
                sbuf[wv][lane] = (int)__float_as_uint(p.x);
            } else if (lane == cnt) {            // zero-weight pad for odd tails
                ebuf[wv][lane] = make_float2(0.f, 0.f);
                sbuf[wv][lane] = 0;
            }
            const int cp = cnt + (cnt & 1);
            #pragma unroll 4
            for (int k = 0; k < cp; k += 2) {
                const int ei = k + h2;
                const int sA = sbuf[wv][ei];
                const float2 w = ebuf[wv][ei];
                const float2 f = *reinterpret_cast<const float2*>(
                    &feat[(size_t)sA * 64 + dp * 2]);
                a00 += f.x * w.x; a01 += f.y * w.x;
                a10 += f.x * w.y; a11 += f.y * w.y;
            }
        }
        #pragma unroll
        for (int m = 32; m; m >>= 1) {
            d0s += __shfl_xor(d0s, m);
            d1s += __shfl_xor(d1s, m);
        }
        a00 += __shfl_xor(a00, 32); a01 += __shfl_xor(a01, 32);
        a10 += __shfl_xor(a10, 32); a11 += __shfl_xor(a11, 32);
        const float r0 = 1.f / d0s, r1 = 1.f / d1s;
        a00 *= r0; a01 *= r0; a10 *= r1; a11 *= r1;
    }
    if (h2 == 0)
        *reinterpret_cast<float2*>(&out[(size_t)n * 128 + dp * 2])      = make_float2(a00, a01);
    else
        *reinterpret_cast<float2*>(&out[(size_t)n * 128 + 64 + dp * 2]) = make_float2(a10, a11);
}

// ---------- minimal-workspace fallback: direct logits + atomic scatter ----------
__global__ __launch_bounds__(256) void logits_direct_kernel(
    const float* __restrict__ feat, const float* __restrict__ nq,
    const int* __restrict__ src, const int* __restrict__ dst,
    const int* __restrict__ rt, const int* __restrict__ nid,
    const float* __restrict__ fc_src, const float* __restrict__ fc_src_b,
    const float* __restrict__ fc_qual, const float* __restrict__ fc_qual_b,
    const float* __restrict__ attn,
    float* __restrict__ e_buf, unsigned* __restrict__ emax)
{
    __shared__ float Ws[64][64];
    __shared__ float Wq[64][64];
    __shared__ float bl[64];
    __shared__ float al[64];
    const int r = blockIdx.y;
    const int t = threadIdx.x;
    for (int i = t; i < 4096; i += 256) {
        ((float*)Ws)[i] = fc_src[(size_t)r * 4096 + i];
        ((float*)Wq)[i] = fc_qual[(size_t)r * 4096 + i];
    }
    if (t < 64) {
        bl[t] = fc_src_b[r * 64 + t] + fc_qual_b[r * 64 + t];
        al[t] = attn[r * 64 + t];
    }
    __syncthreads();

    const int lane = t & 63;
    const int wid = blockIdx.x * 4 + (t >> 6);
    const int nw = gridDim.x * 4;
    for (int e = wid; e < NE; e += nw) {
        if (rt[e] != r) continue;
        const int s = src[e], q = nid[e];
        float fv = feat[(size_t)s * 64 + lane];
        float qv = nq[(size_t)q * 64 + lane];
        float acc = bl[lane];
        for (int k = 0; k < 64; ++k) {
            acc += __shfl(fv, k) * Ws[k][lane];
            acc += __shfl(qv, k) * Wq[k][lane];
        }
        acc = acc > 0.f ? acc : 0.2f * acc;
        float p = acc * al[lane];
        #pragma unroll
        for (int m = 1; m < 32; m <<= 1) p += __shfl_xor(p, m);
        if ((lane & 31) == 0) {
            int h = lane >> 5;
            e_buf[(size_t)e * 2 + h] = p;
            atomicMax(&emax[(size_t)dst[e] * 2 + h], fkey(p));
        }
    }
}

__global__ __launch_bounds__(256) void expdenom_kernel(
    const int* __restrict__ dst, float* __restrict__ e_buf,
    const unsigned* __restrict__ emax, float* __restrict__ denom)
{
    const int i = blockIdx.x * 256 + threadIdx.x;
    if (i >= NE * 2) return;
    const int e = i >> 1, h = i & 1;
    const int dn = dst[e];
    const float m = funkey(emax[(size_t)dn * 2 + h]);
    const float ex = __expf(e_buf[i] - m);
    e_buf[i] = ex;
    unsafeAtomicAdd(&denom[(size_t)dn * 2 + h], ex);
}

__global__ __launch_bounds__(256) void scatter_kernel(
    const float* __restrict__ feat, const int* __restrict__ src, const int* __restrict__ dst,
    const float* __restrict__ ex, const float* __restrict__ denom, float* __restrict__ out)
{
    const int e = blockIdx.x * 4 + (threadIdx.x >> 6);
    if (e >= NE) return;
    const int lane = threadIdx.x & 63;
    const int s = src[e], dn = dst[e];
    const float f = feat[(size_t)s * 64 + lane];
    const float a0 = ex[(size_t)e * 2]     / denom[(size_t)dn * 2];
    const float a1 = ex[(size_t)e * 2 + 1] / denom[(size_t)dn * 2 + 1];
    unsafeAtomicAdd(&out[(size_t)dn * 128 + lane],      f * a0);
    unsafeAtomicAdd(&out[(size_t)dn * 128 + 64 + lane], f * a1);
}

extern "C" void kernel_launch(void* const* d_in, const int* in_sizes, int n_in,
                              void* d_out, int out_size, void* d_ws, size_t ws_size,
                              hipStream_t stream)
{
    const float* feat      = (const float*)d_in[0];
    const int*   src       = (const int*)d_in[1];
    const int*   dst       = (const int*)d_in[2];
    const int*   rt        = (const int*)d_in[3];
    const int*   nid       = (const int*)d_in[4];
    const float* fc_src    = (const float*)d_in[5];
    const float* fc_src_b  = (const float*)d_in[6];
    const float* nq        = (const float*)d_in[7];
    const float* fc_qual   = (const float*)d_in[8];
    const float* fc_qual_b = (const float*)d_in[9];
    const float* attn      = (const float*)d_in[10];
    float* out = (float*)d_out;

    char* ws = (char*)d_ws;

    // ---- layout (no aliasing; ~32 MB total) ----
    int*    cnt      = (int*)ws;                            // NN           @0
    int*    cursor   = (int*)(ws + 262144);                 // NN
    int*    offs     = (int*)(ws + 524288);                 // NN+1
    int*    partial  = (int*)(ws + 786432);                 // 256
    int*    cnt_r    = (int*)(ws + 800000);                 // 8
    int*    off_pad  = (int*)(ws + 800064);                 // 9
    int*    cursor_r = (int*)(ws + 800128);                 // 8
    int*    re       = (int*)(ws + 1048576);                // NE+512
    float4* perm     = (float4*)(ws + 5242880);             // NE float4 (12.8MB)
    unsigned short* xS  = (unsigned short*)(ws + 18874368); // 6.4MB
    unsigned short* xQ  = (unsigned short*)(ws + 25274368); // 6.4MB
    unsigned short* WtS = (unsigned short*)(ws + 31674368); // 64KB
    unsigned short* WtQ = (unsigned short*)(ws + 31739904); // 64KB
    float*          bSQ = (float*)(ws + 31805440);          // 2KB
    const size_t need = 31807488;

    if (ws_size >= need) {
        prep_kernel<<<(2 * (NN * 64 / 4) + 65536 + 512 + 255) / 256, 256, 0, stream>>>(
            feat, nq, fc_src, fc_qual, fc_src_b, fc_qual_b, xS, xQ, WtS, WtQ, bSQ);

        hipMemsetAsync(ws, 0, 524288, stream);              // cnt + cursor
        hipMemsetAsync(ws + 800000, 0, 256, stream);        // cnt_r/off_pad/cursor_r
        hipMemsetAsync(re, 0xFF, (size_t)(NE + 512) * 4, stream);

        hist_kernel<<<(NE + 255) / 256, 256, 0, stream>>>(dst, rt, cnt, cnt_r);
        const int nblk = (NN + 255) / 256;
        scan1_kernel<<<nblk, 256, 0, stream>>>(cnt, offs, partial);
        scan2_kernel<<<1, 256, 0, stream>>>(partial, nblk);
        scan3_kernel<<<nblk, 256, 0, stream>>>(offs, partial);
        scanr_kernel<<<1, 64, 0, stream>>>(cnt_r, off_pad, cursor_r);
        fillr_kernel<<<(NE + 255) / 256, 256, 0, stream>>>(rt, cursor_r, re);

        const int nwave = (NE + 512 + 63) / 64;             // upper bound on padded slots/64
        logits_kernel<<<(nwave + 3) / 4, 256, 0, stream>>>(
            xS, xQ, WtS, WtQ, bSQ, attn, src, dst, nid,
            re, off_pad, offs, cursor, perm);
        aggregate_kernel<<<(NN + 3) / 4, 256, 0, stream>>>(feat, offs, perm, out);
    } else {
        // minimal-workspace fallback (atomic path)
        float*    e_buf = (float*)ws;
        unsigned* emax  = (unsigned*)(ws + (size_t)NE * 2 * 4);
        float*    denom = (float*)(ws + (size_t)NE * 2 * 4 + (size_t)NN * 2 * 4);
        hipMemsetAsync(out, 0, (size_t)out_size * sizeof(float), stream);
        hipMemsetAsync(emax, 0, (size_t)NN * 2 * 4 * 2, stream);
        dim3 g(256, NR);
        logits_direct_kernel<<<g, 256, 0, stream>>>(
            feat, nq, src, dst, rt, nid, fc_src, fc_src_b, fc_qual, fc_qual_b,
            attn, e_buf, emax);
        expdenom_kernel<<<(NE * 2 + 255) / 256, 256, 0, stream>>>(dst, e_buf, emax, denom);
        scatter_kernel<<<(NE + 3) / 4, 256, 0, stream>>>(feat, src, dst, e_buf, denom, out);
    }
}

// Round 8
// 214.050 us; speedup vs baseline: 1.3182x; 1.1253x over previous
//
#include <hip/hip_runtime.h>
#include <hip/hip_bf16.h>

#define NN 50000
#define NR 8
#define NE 800000

typedef short bf16x8 __attribute__((ext_vector_type(8)));
typedef float f32x4  __attribute__((ext_vector_type(4)));

// ---------- helpers ----------
__device__ __forceinline__ unsigned fkey(float f) {
    unsigned b = __float_as_uint(f);
    return (b & 0x80000000u) ? ~b : (b | 0x80000000u);
}
__device__ __forceinline__ float funkey(unsigned k) {
    unsigned b = (k & 0x80000000u) ? (k ^ 0x80000000u) : ~k;
    return __uint_as_float(b);
}
__device__ __forceinline__ unsigned short f2bf(float f) {
    unsigned u = __float_as_uint(f);
    unsigned r = (u + 0x7FFFu + ((u >> 16) & 1u)) >> 16;
    return (unsigned short)r;
}
__device__ __forceinline__ float bf2f(unsigned short b) {
    return __uint_as_float(((unsigned)b) << 16);
}

// ---------- P0: x->bf16 tables, W->Wt[r][o][k] bf16, bias sums, + fused histograms ----------
__global__ __launch_bounds__(256) void prep_hist_kernel(
    const float* __restrict__ feat, const float* __restrict__ nq,
    const float* __restrict__ WS, const float* __restrict__ WQ,
    const float* __restrict__ bS, const float* __restrict__ bQ,
    const int* __restrict__ dst, const int* __restrict__ rt,
    unsigned short* __restrict__ xS, unsigned short* __restrict__ xQ,
    unsigned short* __restrict__ WtS, unsigned short* __restrict__ WtQ,
    float* __restrict__ bSQ, int* __restrict__ cnt, int* __restrict__ cnt_r)
{
    __shared__ int h[8];
    const int t = threadIdx.x;
    if (t < 8) h[t] = 0;
    __syncthreads();
    const int idx = blockIdx.x * 256 + t;
    if (idx < NE) {
        atomicAdd(&cnt[dst[idx]], 1);
        atomicAdd(&h[rt[idx]], 1);
    }
    const int NX = NN * 64 / 4;                      // 800000 float4s per table
    if (idx < NX) {
        const float4 v = reinterpret_cast<const float4*>(feat)[idx];
        ushort4 p; p.x = f2bf(v.x); p.y = f2bf(v.y); p.z = f2bf(v.z); p.w = f2bf(v.w);
        reinterpret_cast<ushort4*>(xS)[idx] = p;
    } else if (idx < 2 * NX) {
        const float4 v = reinterpret_cast<const float4*>(nq)[idx - NX];
        ushort4 p; p.x = f2bf(v.x); p.y = f2bf(v.y); p.z = f2bf(v.z); p.w = f2bf(v.w);
        reinterpret_cast<ushort4*>(xQ)[idx - NX] = p;
    } else {
        int i = idx - 2 * NX;
        if (i < 32768) {
            const int r = i >> 12, rem = i & 4095, o = rem >> 6, k = rem & 63;
            WtS[i] = f2bf(WS[(size_t)r * 4096 + k * 64 + o]);
        } else if (i < 65536) {
            i -= 32768;
            const int r = i >> 12, rem = i & 4095, o = rem >> 6, k = rem & 63;
            WtQ[i] = f2bf(WQ[(size_t)r * 4096 + k * 64 + o]);
        } else if (i < 65536 + 512) {
            const int j = i - 65536;
            bSQ[j] = bS[j] + bQ[j];
        }
    }
    __syncthreads();
    if (t < 8 && h[t]) atomicAdd(&cnt_r[t], h[t]);
}

// ---------- dst-CSR scan ----------
__global__ __launch_bounds__(256) void scan1_kernel(
    const int* __restrict__ cnt, int* __restrict__ offs, int* __restrict__ partial)
{
    __shared__ int s[256];
    const int t = threadIdx.x, i = blockIdx.x * 256 + t;
    const int v = (i < NN) ? cnt[i] : 0;
    s[t] = v;
    __syncthreads();
    #pragma unroll
    for (int off = 1; off < 256; off <<= 1) {
        const int x = (t >= off) ? s[t - off] : 0;
        __syncthreads();
        s[t] += x;
        __syncthreads();
    }
    if (i < NN) offs[i] = s[t] - v;
    if (t == 255) partial[blockIdx.x] = s[255];
}

// scan2 + relation-bucket offsets (padded to 256) + pad-slot meta fill
__global__ __launch_bounds__(256) void scan2_kernel(
    int* __restrict__ partial, const int nblk,
    const int* __restrict__ cnt_r, int* __restrict__ off_pad,
    int* __restrict__ cursor_r, int4* __restrict__ meta)
{
    __shared__ int s[256];
    __shared__ int sop[9];
    const int t = threadIdx.x;
    const int v = (t < nblk) ? partial[t] : 0;
    s[t] = v;
    __syncthreads();
    #pragma unroll
    for (int off = 1; off < 256; off <<= 1) {
        const int x = (t >= off) ? s[t - off] : 0;
        __syncthreads();
        s[t] += x;
        __syncthreads();
    }
    if (t < nblk) partial[t] = s[t] - v;
    if (t == 0) {
        int acc = 0;
        for (int r = 0; r < NR; ++r) {
            sop[r] = acc; off_pad[r] = acc; cursor_r[r] = acc;
            acc += (cnt_r[r] + 255) & ~255;
        }
        sop[8] = acc; off_pad[8] = acc;
    }
    __syncthreads();
    for (int r = 0; r < NR; ++r) {
        const int s0 = sop[r] + cnt_r[r], s1 = sop[r + 1];
        for (int i = s0 + t; i < s1; i += 256) meta[i] = make_int4(0, 0, -1, 0);
    }
}

__global__ __launch_bounds__(256) void scan3_kernel(
    int* __restrict__ offs, const int* __restrict__ partial)
{
    const int i = blockIdx.x * 256 + threadIdx.x;
    if (i < NN) offs[i] += partial[blockIdx.x];
    if (i == 0) offs[NN] = NE;
}

// ---------- fillr: relation counting-sort + dst-CSR slot assignment -> meta {src,nid,jslot} ----------
__global__ __launch_bounds__(256) void fillr_kernel(
    const int* __restrict__ rt, const int* __restrict__ src,
    const int* __restrict__ nid, const int* __restrict__ dst,
    const int* __restrict__ offs, int* __restrict__ cursor,
    int* __restrict__ cursor_r, int4* __restrict__ meta)
{
    __shared__ int lh[8], base[8];
    const int t = threadIdx.x;
    if (t < 8) lh[t] = 0;
    __syncthreads();
    const int e = blockIdx.x * 256 + t;
    int r = 0, rank = 0;
    if (e < NE) {
        r = rt[e];
        rank = atomicAdd(&lh[r], 1);
    }
    __syncthreads();
    if (t < 8 && lh[t]) base[t] = atomicAdd(&cursor_r[t], lh[t]);
    __syncthreads();
    if (e < NE) {
        const int dn = dst[e];
        const int j = offs[dn] + atomicAdd(&cursor[dn], 1);
        meta[base[r] + rank] = make_int4(src[e], nid[e], j, 0);
    }
}

// ---------- K2: batched per-edge MFMA logits, LDS-staged W, no atomics ----------
// One block = 256 edges of one relation; one wave = 64 edges (4 sub-batches of 16).
__global__ __launch_bounds__(256) void logits_kernel(
    const unsigned short* __restrict__ xS, const unsigned short* __restrict__ xQ,
    const unsigned short* __restrict__ WtS, const unsigned short* __restrict__ WtQ,
    const float* __restrict__ bSQ, const float* __restrict__ attn,
    const int4* __restrict__ meta, const int* __restrict__ off_pad,
    float4* __restrict__ perm)
{
    __shared__ bf16x8 ldsS[512];   // 8KB, XOR-swizzled chunks
    __shared__ bf16x8 ldsQ[512];
    const int slot0 = blockIdx.x * 256;
    int r = 0;
    #pragma unroll
    for (int i = 1; i <= 8; ++i) r += (slot0 >= off_pad[i]);
    if (r >= 8) return;                       // past the end (block-uniform)

    const int t = threadIdx.x;
    for (int c = t; c < 512; c += 256) {      // stage W[r] swizzled
        const int row = c >> 3, c8 = c & 7, sw = c8 ^ (row & 7);
        ldsS[row * 8 + sw] = *reinterpret_cast<const bf16x8*>(WtS + (size_t)r * 4096 + c * 8);
        ldsQ[row * 8 + sw] = *reinterpret_cast<const bf16x8*>(WtQ + (size_t)r * 4096 + c * 8);
    }
    __syncthreads();

    const int lane = t & 63, l15 = lane & 15, g = lane >> 4, l7 = l15 & 7;
    const int sbase = slot0 + (t >> 6) * 64;

    int4 mt[4];
    #pragma unroll
    for (int b = 0; b < 4; ++b) mt[b] = meta[sbase + b * 16 + l15];

    bf16x8 xf[4][2], qf[4][2];                // 16 independent 16B gathers in flight
    #pragma unroll
    for (int b = 0; b < 4; ++b) {
        const unsigned short* xp = xS + (size_t)mt[b].x * 64;
        const unsigned short* qp = xQ + (size_t)mt[b].y * 64;
        xf[b][0] = *reinterpret_cast<const bf16x8*>(xp + g * 8);
        xf[b][1] = *reinterpret_cast<const bf16x8*>(xp + 32 + g * 8);
        qf[b][0] = *reinterpret_cast<const bf16x8*>(qp + g * 8);
        qf[b][1] = *reinterpret_cast<const bf16x8*>(qp + 32 + g * 8);
    }

    float p0[4] = {0.f, 0.f, 0.f, 0.f}, p1[4] = {0.f, 0.f, 0.f, 0.f};
    #pragma unroll
    for (int ot = 0; ot < 4; ++ot) {
        const int row8 = (ot * 16 + l15) * 8;
        const bf16x8 wS0 = ldsS[row8 + (g ^ l7)];
        const bf16x8 wS1 = ldsS[row8 + ((4 + g) ^ l7)];
        const bf16x8 wQ0 = ldsQ[row8 + (g ^ l7)];
        const bf16x8 wQ1 = ldsQ[row8 + ((4 + g) ^ l7)];
        const f32x4 bv = *reinterpret_cast<const f32x4*>(bSQ  + r * 64 + ot * 16 + g * 4);
        const f32x4 av = *reinterpret_cast<const f32x4*>(attn + r * 64 + ot * 16 + g * 4);
        #pragma unroll
        for (int b = 0; b < 4; ++b) {
            f32x4 acc = (f32x4){0.f, 0.f, 0.f, 0.f};
            acc = __builtin_amdgcn_mfma_f32_16x16x32_bf16(wS0, xf[b][0], acc, 0, 0, 0);
            acc = __builtin_amdgcn_mfma_f32_16x16x32_bf16(wS1, xf[b][1], acc, 0, 0, 0);
            acc = __builtin_amdgcn_mfma_f32_16x16x32_bf16(wQ0, qf[b][0], acc, 0, 0, 0);
            acc = __builtin_amdgcn_mfma_f32_16x16x32_bf16(wQ1, qf[b][1], acc, 0, 0, 0);
            float part = 0.f;
            #pragma unroll
            for (int j = 0; j < 4; ++j) {
                float v = acc[j] + bv[j];
                v = v > 0.f ? v : 0.2f * v;
                part += v * av[j];
            }
            if (ot < 2) p0[b] += part; else p1[b] += part;
        }
    }
    #pragma unroll
    for (int b = 0; b < 4; ++b) {
        p0[b] += __shfl_xor(p0[b], 16); p0[b] += __shfl_xor(p0[b], 32);
        p1[b] += __shfl_xor(p1[b], 16); p1[b] += __shfl_xor(p1[b], 32);
        if (g == 0 && mt[b].z >= 0)
            perm[mt[b].z] = make_float4(__int_as_float(mt[b].x), p0[b], p1[b], 0.f);
    }
}

// ---------- K4: per-node softmax + aggregation (bf16 feat gathers) ----------
__global__ __launch_bounds__(256) void aggregate_kernel(
    const unsigned short* __restrict__ xS, const int* __restrict__ offs,
    const float4* __restrict__ perm, float* __restrict__ out)
{
    __shared__ float2 ebuf[4][64];
    __shared__ int    sbuf[4][64];
    const int wv = threadIdx.x >> 6;
    const int n = blockIdx.x * 4 + wv;
    if (n >= NN) return;
    const int lane = threadIdx.x & 63;
    const int h2 = lane >> 5;        // which edge of the pair
    const int dp = lane & 31;        // d-pair: covers d = 2dp, 2dp+1
    const int s0 = offs[n], s1 = offs[n + 1];
    float a00 = 0.f, a01 = 0.f, a10 = 0.f, a11 = 0.f;   // [head][even/odd d]
    float d0s = 0.f, d1s = 0.f;
    if (s1 > s0) {
        float m0 = -1e30f, m1 = -1e30f;
        for (int j = s0 + lane; j < s1; j += 64) {
            const float4 p = perm[j];
            m0 = fmaxf(m0, p.y); m1 = fmaxf(m1, p.z);
        }
        #pragma unroll
        for (int m = 32; m; m >>= 1) {
            m0 = fmaxf(m0, __shfl_xor(m0, m));
            m1 = fmaxf(m1, __shfl_xor(m1, m));
        }
        for (int c = s0; c < s1; c += 64) {
            const int cnt = min(64, s1 - c);
            if (lane < cnt) {
                const float4 p = perm[c + lane];
                const float e0 = __expf(p.y - m0);
                const float e1 = __expf(p.z - m1);
                d0s += e0; d1s += e1;
                ebuf[wv][lane] = make_float2(e0, e1);
                sbuf[wv][lane] = (int)__float_as_uint(p.x);
            } else if (lane == cnt) {            // zero-weight pad for odd tails
                ebuf[wv][lane] = make_float2(0.f, 0.f);
                sbuf[wv][lane] = 0;
            }
            const int cp = cnt + (cnt & 1);
            #pragma unroll 4
            for (int k = 0; k < cp; k += 2) {
                const int ei = k + h2;
                const int sA = sbuf[wv][ei];
                const float2 w = ebuf[wv][ei];
                const unsigned fv = *reinterpret_cast<const unsigned*>(
                    xS + (size_t)sA * 64 + dp * 2);
                const float fx = bf2f((unsigned short)(fv & 0xFFFFu));
                const float fy = bf2f((unsigned short)(fv >> 16));
                a00 += fx * w.x; a01 += fy * w.x;
                a10 += fx * w.y; a11 += fy * w.y;
            }
        }
        #pragma unroll
        for (int m = 32; m; m >>= 1) {
            d0s += __shfl_xor(d0s, m);
            d1s += __shfl_xor(d1s, m);
        }
        a00 += __shfl_xor(a00, 32); a01 += __shfl_xor(a01, 32);
        a10 += __shfl_xor(a10, 32); a11 += __shfl_xor(a11, 32);
        const float r0 = 1.f / d0s, r1 = 1.f / d1s;
        a00 *= r0; a01 *= r0; a10 *= r1; a11 *= r1;
    }
    if (h2 == 0)
        *reinterpret_cast<float2*>(&out[(size_t)n * 128 + dp * 2])      = make_float2(a00, a01);
    else
        *reinterpret_cast<float2*>(&out[(size_t)n * 128 + 64 + dp * 2]) = make_float2(a10, a11);
}

// ---------- minimal-workspace fallback: direct logits + atomic scatter ----------
__global__ __launch_bounds__(256) void logits_direct_kernel(
    const float* __restrict__ feat, const float* __restrict__ nq,
    const int* __restrict__ src, const int* __restrict__ dst,
    const int* __restrict__ rt, const int* __restrict__ nid,
    const float* __restrict__ fc_src, const float* __restrict__ fc_src_b,
    const float* __restrict__ fc_qual, const float* __restrict__ fc_qual_b,
    const float* __restrict__ attn,
    float* __restrict__ e_buf, unsigned* __restrict__ emax)
{
    __shared__ float Ws[64][64];
    __shared__ float Wq[64][64];
    __shared__ float bl[64];
    __shared__ float al[64];
    const int r = blockIdx.y;
    const int t = threadIdx.x;
    for (int i = t; i < 4096; i += 256) {
        ((float*)Ws)[i] = fc_src[(size_t)r * 4096 + i];
        ((float*)Wq)[i] = fc_qual[(size_t)r * 4096 + i];
    }
    if (t < 64) {
        bl[t] = fc_src_b[r * 64 + t] + fc_qual_b[r * 64 + t];
        al[t] = attn[r * 64 + t];
    }
    __syncthreads();

    const int lane = t & 63;
    const int wid = blockIdx.x * 4 + (t >> 6);
    const int nw = gridDim.x * 4;
    for (int e = wid; e < NE; e += nw) {
        if (rt[e] != r) continue;
        const int s = src[e], q = nid[e];
        float fv = feat[(size_t)s * 64 + lane];
        float qv = nq[(size_t)q * 64 + lane];
        float acc = bl[lane];
        for (int k = 0; k < 64; ++k) {
            acc += __shfl(fv, k) * Ws[k][lane];
            acc += __shfl(qv, k) * Wq[k][lane];
        }
        acc = acc > 0.f ? acc : 0.2f * acc;
        float p = acc * al[lane];
        #pragma unroll
        for (int m = 1; m < 32; m <<= 1) p += __shfl_xor(p, m);
        if ((lane & 31) == 0) {
            int h = lane >> 5;
            e_buf[(size_t)e * 2 + h] = p;
            atomicMax(&emax[(size_t)dst[e] * 2 + h], fkey(p));
        }
    }
}

__global__ __launch_bounds__(256) void expdenom_kernel(
    const int* __restrict__ dst, float* __restrict__ e_buf,
    const unsigned* __restrict__ emax, float* __restrict__ denom)
{
    const int i = blockIdx.x * 256 + threadIdx.x;
    if (i >= NE * 2) return;
    const int e = i >> 1, h = i & 1;
    const int dn = dst[e];
    const float m = funkey(emax[(size_t)dn * 2 + h]);
    const float ex = __expf(e_buf[i] - m);
    e_buf[i] = ex;
    unsafeAtomicAdd(&denom[(size_t)dn * 2 + h], ex);
}

__global__ __launch_bounds__(256) void scatter_kernel(
    const float* __restrict__ feat, const int* __restrict__ src, const int* __restrict__ dst,
    const float* __restrict__ ex, const float* __restrict__ denom, float* __restrict__ out)
{
    const int e = blockIdx.x * 4 + (threadIdx.x >> 6);
    if (e >= NE) return;
    const int lane = threadIdx.x & 63;
    const int s = src[e], dn = dst[e];
    const float f = feat[(size_t)s * 64 + lane];
    const float a0 = ex[(size_t)e * 2]     / denom[(size_t)dn * 2];
    const float a1 = ex[(size_t)e * 2 + 1] / denom[(size_t)dn * 2 + 1];
    unsafeAtomicAdd(&out[(size_t)dn * 128 + lane],      f * a0);
    unsafeAtomicAdd(&out[(size_t)dn * 128 + 64 + lane], f * a1);
}

extern "C" void kernel_launch(void* const* d_in, const int* in_sizes, int n_in,
                              void* d_out, int out_size, void* d_ws, size_t ws_size,
                              hipStream_t stream)
{
    const float* feat      = (const float*)d_in[0];
    const int*   src       = (const int*)d_in[1];
    const int*   dst       = (const int*)d_in[2];
    const int*   rt        = (const int*)d_in[3];
    const int*   nid       = (const int*)d_in[4];
    const float* fc_src    = (const float*)d_in[5];
    const float* fc_src_b  = (const float*)d_in[6];
    const float* nq        = (const float*)d_in[7];
    const float* fc_qual   = (const float*)d_in[8];
    const float* fc_qual_b = (const float*)d_in[9];
    const float* attn      = (const float*)d_in[10];
    float* out = (float*)d_out;

    char* ws = (char*)d_ws;

    // ---- layout (~40 MB, no aliasing) ----
    int*    cnt      = (int*)ws;                            // NN       @0        (zeroed)
    int*    cursor   = (int*)(ws + 262144);                 // NN                 (zeroed)
    int*    cnt_r    = (int*)(ws + 524288);                 // 8                  (zeroed)
    int*    offs     = (int*)(ws + 589824);                 // NN+1
    int*    partial  = (int*)(ws + 851968);                 // 256
    int*    off_pad  = (int*)(ws + 856064);                 // 9
    int*    cursor_r = (int*)(ws + 856192);                 // 8
    int4*   meta     = (int4*)(ws + 1048576);               // NE+2048 slots (12.83MB)
    float4* perm     = (float4*)(ws + 14000000);            // NE float4 (12.8MB)
    unsigned short* xS  = (unsigned short*)(ws + 26800000); // 6.4MB
    unsigned short* xQ  = (unsigned short*)(ws + 33200000); // 6.4MB
    unsigned short* WtS = (unsigned short*)(ws + 39600000); // 64KB
    unsigned short* WtQ = (unsigned short*)(ws + 39665536); // 64KB
    float*          bSQ = (float*)(ws + 39731072);          // 2KB
    const size_t need = 39733120;

    if (ws_size >= need) {
        hipMemsetAsync(ws, 0, 524352, stream);              // cnt + cursor + cnt_r

        prep_hist_kernel<<<6508, 256, 0, stream>>>(
            feat, nq, fc_src, fc_qual, fc_src_b, fc_qual_b, dst, rt,
            xS, xQ, WtS, WtQ, bSQ, cnt, cnt_r);

        const int nblk = (NN + 255) / 256;                  // 196
        scan1_kernel<<<nblk, 256, 0, stream>>>(cnt, offs, partial);
        scan2_kernel<<<1, 256, 0, stream>>>(partial, nblk, cnt_r, off_pad, cursor_r, meta);
        scan3_kernel<<<nblk, 256, 0, stream>>>(offs, partial);
        fillr_kernel<<<(NE + 255) / 256, 256, 0, stream>>>(
            rt, src, nid, dst, offs, cursor, cursor_r, meta);

        logits_kernel<<<(NE + 8 * 256) / 256, 256, 0, stream>>>(
            xS, xQ, WtS, WtQ, bSQ, attn, meta, off_pad, perm);
        aggregate_kernel<<<(NN + 3) / 4, 256, 0, stream>>>(xS, offs, perm, out);
    } else {
        // minimal-workspace fallback (atomic path)
        float*    e_buf = (float*)ws;
        unsigned* emax  = (unsigned*)(ws + (size_t)NE * 2 * 4);
        float*    denom = (float*)(ws + (size_t)NE * 2 * 4 + (size_t)NN * 2 * 4);
        hipMemsetAsync(out, 0, (size_t)out_size * sizeof(float), stream);
        hipMemsetAsync(emax, 0, (size_t)NN * 2 * 4 * 2, stream);
        dim3 g(256, NR);
        logits_direct_kernel<<<g, 256, 0, stream>>>(
            feat, nq, src, dst, rt, nid, fc_src, fc_src_b, fc_qual, fc_qual_b,
            attn, e_buf, emax);
        expdenom_kernel<<<(NE * 2 + 255) / 256, 256, 0, stream>>>(dst, e_buf, emax, denom);
        scatter_kernel<<<(NE + 3) / 4, 256, 0, stream>>>(feat, src, dst, e_buf, denom, out);
    }
}

// Round 9
// 206.399 us; speedup vs baseline: 1.3670x; 1.0371x over previous
//
#include <hip/hip_runtime.h>
#include <hip/hip_bf16.h>

#define NN 50000
#define NR 8
#define NE 800000
#define NBLK_E 3125    // NE / 256 exactly

typedef short bf16x8 __attribute__((ext_vector_type(8)));
typedef float f32x4  __attribute__((ext_vector_type(4)));

// ---------- helpers ----------
__device__ __forceinline__ unsigned fkey(float f) {
    unsigned b = __float_as_uint(f);
    return (b & 0x80000000u) ? ~b : (b | 0x80000000u);
}
__device__ __forceinline__ float funkey(unsigned k) {
    unsigned b = (k & 0x80000000u) ? (k ^ 0x80000000u) : ~k;
    return __uint_as_float(b);
}
__device__ __forceinline__ unsigned short f2bf(float f) {
    unsigned u = __float_as_uint(f);
    unsigned r = (u + 0x7FFFu + ((u >> 16) & 1u)) >> 16;
    return (unsigned short)r;
}
__device__ __forceinline__ float bf2f(unsigned short b) {
    return __uint_as_float(((unsigned)b) << 16);
}

// ---------- P0: x->bf16, W->Wt bf16, bias sums, dst histogram, per-block relation hist ----------
__global__ __launch_bounds__(256) void prep_hist_kernel(
    const float* __restrict__ feat, const float* __restrict__ nq,
    const float* __restrict__ WS, const float* __restrict__ WQ,
    const float* __restrict__ bS, const float* __restrict__ bQ,
    const int* __restrict__ dst, const int* __restrict__ rt,
    unsigned short* __restrict__ xS, unsigned short* __restrict__ xQ,
    unsigned short* __restrict__ WtS, unsigned short* __restrict__ WtQ,
    float* __restrict__ bSQ, int* __restrict__ cnt, int* __restrict__ cnt_r,
    int* __restrict__ rhist)
{
    __shared__ int wcnt[4][8];
    const int t = threadIdx.x;
    const int idx = blockIdx.x * 256 + t;

    if (blockIdx.x < NBLK_E) {                       // edge blocks (exact cover)
        const int w = t >> 6, lane = t & 63;
        const int r = rt[idx];
        atomicAdd(&cnt[dst[idx]], 1);
        #pragma unroll
        for (int rr = 0; rr < 8; ++rr) {
            const unsigned long long m = __ballot(r == rr);
            if (lane == 0) wcnt[w][rr] = __popcll(m);
        }
        __syncthreads();
        if (t < 8) {
            const int s = wcnt[0][t] + wcnt[1][t] + wcnt[2][t] + wcnt[3][t];
            rhist[t * NBLK_E + blockIdx.x] = s;
            if (s) atomicAdd(&cnt_r[t], s);          // fire-and-forget (no return)
        }
    }

    const int NX = NN * 64 / 4;                      // 800000 float4s per table
    if (idx < NX) {
        const float4 v = reinterpret_cast<const float4*>(feat)[idx];
        ushort4 p; p.x = f2bf(v.x); p.y = f2bf(v.y); p.z = f2bf(v.z); p.w = f2bf(v.w);
        reinterpret_cast<ushort4*>(xS)[idx] = p;
    } else if (idx < 2 * NX) {
        const float4 v = reinterpret_cast<const float4*>(nq)[idx - NX];
        ushort4 p; p.x = f2bf(v.x); p.y = f2bf(v.y); p.z = f2bf(v.z); p.w = f2bf(v.w);
        reinterpret_cast<ushort4*>(xQ)[idx - NX] = p;
    } else {
        int i = idx - 2 * NX;
        if (i < 32768) {
            const int r = i >> 12, rem = i & 4095, o = rem >> 6, k = rem & 63;
            WtS[i] = f2bf(WS[(size_t)r * 4096 + k * 64 + o]);
        } else if (i < 65536) {
            i -= 32768;
            const int r = i >> 12, rem = i & 4095, o = rem >> 6, k = rem & 63;
            WtQ[i] = f2bf(WQ[(size_t)r * 4096 + k * 64 + o]);
        } else if (i < 65536 + 512) {
            const int j = i - 65536;
            bSQ[j] = bS[j] + bQ[j];
        }
    }
}

// ---------- dst-CSR scan ----------
__global__ __launch_bounds__(256) void scan1_kernel(
    const int* __restrict__ cnt, int* __restrict__ offs, int* __restrict__ partial)
{
    __shared__ int s[256];
    const int t = threadIdx.x, i = blockIdx.x * 256 + t;
    const int v = (i < NN) ? cnt[i] : 0;
    s[t] = v;
    __syncthreads();
    #pragma unroll
    for (int off = 1; off < 256; off <<= 1) {
        const int x = (t >= off) ? s[t - off] : 0;
        __syncthreads();
        s[t] += x;
        __syncthreads();
    }
    if (i < NN) offs[i] = s[t] - v;
    if (t == 255) partial[blockIdx.x] = s[255];
}

// scan2 + relation-bucket offsets (padded to 256) + pad-slot meta fill
__global__ __launch_bounds__(256) void scan2_kernel(
    int* __restrict__ partial, const int nblk,
    const int* __restrict__ cnt_r, int* __restrict__ off_pad, int4* __restrict__ meta)
{
    __shared__ int s[256];
    __shared__ int sop[9];
    const int t = threadIdx.x;
    const int v = (t < nblk) ? partial[t] : 0;
    s[t] = v;
    __syncthreads();
    #pragma unroll
    for (int off = 1; off < 256; off <<= 1) {
        const int x = (t >= off) ? s[t - off] : 0;
        __syncthreads();
        s[t] += x;
        __syncthreads();
    }
    if (t < nblk) partial[t] = s[t] - v;
    if (t == 0) {
        int acc = 0;
        for (int r = 0; r < NR; ++r) {
            sop[r] = acc; off_pad[r] = acc;
            acc += (cnt_r[r] + 255) & ~255;
        }
        sop[8] = acc; off_pad[8] = acc;
    }
    __syncthreads();
    for (int r = 0; r < NR; ++r) {
        const int s0 = sop[r] + cnt_r[r], s1 = sop[r + 1];
        for (int i = s0 + t; i < s1; i += 256) meta[i] = make_int4(0, 0, -1, 0);
    }
}

// scan3: finalize offs, and initialize cursor = offs (fused slot base)
__global__ __launch_bounds__(256) void scan3_kernel(
    int* __restrict__ offs, const int* __restrict__ partial, int* __restrict__ cursor)
{
    const int i = blockIdx.x * 256 + threadIdx.x;
    if (i < NN) {
        const int v = offs[i] + partial[blockIdx.x];
        offs[i] = v;
        cursor[i] = v;
    }
    if (i == 0) offs[NN] = NE;
}

// ---------- scanrb: per-relation exclusive scan of per-block histograms ----------
__global__ __launch_bounds__(256) void scanrb_kernel(
    const int* __restrict__ rhist, const int* __restrict__ off_pad, int* __restrict__ rbase)
{
    __shared__ int s[256];
    __shared__ int carry;
    const int r = blockIdx.x;                   // 8 blocks
    const int t = threadIdx.x;
    if (t == 0) carry = off_pad[r];
    __syncthreads();
    for (int b0 = 0; b0 < NBLK_E; b0 += 256) {
        const int i = b0 + t;
        const int v = (i < NBLK_E) ? rhist[r * NBLK_E + i] : 0;
        s[t] = v;
        __syncthreads();
        #pragma unroll
        for (int off = 1; off < 256; off <<= 1) {
            const int x = (t >= off) ? s[t - off] : 0;
            __syncthreads();
            s[t] += x;
            __syncthreads();
        }
        if (i < NBLK_E) rbase[r * NBLK_E + i] = carry + s[t] - v;
        __syncthreads();
        if (t == 0) carry += s[255];
        __syncthreads();
    }
}

// ---------- fillr: ballot-ranked relation sort (no relation atomics) + dst slot ----------
__global__ __launch_bounds__(256) void fillr_kernel(
    const int* __restrict__ rt, const int* __restrict__ src,
    const int* __restrict__ nid, const int* __restrict__ dst,
    int* __restrict__ cursor, const int* __restrict__ rbase,
    int4* __restrict__ meta)
{
    __shared__ int wcnt[4][8];
    __shared__ int wbase[4][8];
    const int t = threadIdx.x, e = blockIdx.x * 256 + t;
    const int w = t >> 6, lane = t & 63;
    const int r = rt[e];
    unsigned long long mymask = 0;
    #pragma unroll
    for (int rr = 0; rr < 8; ++rr) {
        const unsigned long long m = __ballot(r == rr);
        if (lane == 0) wcnt[w][rr] = __popcll(m);
        if (r == rr) mymask = m;
    }
    const int rank = (int)__popcll(mymask & ((1ull << lane) - 1ull));
    __syncthreads();
    if (t < 32) {
        const int rr = t & 7, ww = t >> 3;
        int b = rbase[rr * NBLK_E + blockIdx.x];
        for (int w2 = 0; w2 < ww; ++w2) b += wcnt[w2][rr];
        wbase[ww][rr] = b;
    }
    __syncthreads();
    const int slot = wbase[w][r] + rank;
    const int j = atomicAdd(&cursor[dst[e]], 1);
    meta[slot] = make_int4(src[e], nid[e], j, 0);
}

// ---------- K2: batched per-edge MFMA logits, LDS-staged W, no atomics ----------
__global__ __launch_bounds__(256) void logits_kernel(
    const unsigned short* __restrict__ xS, const unsigned short* __restrict__ xQ,
    const unsigned short* __restrict__ WtS, const unsigned short* __restrict__ WtQ,
    const float* __restrict__ bSQ, const float* __restrict__ attn,
    const int4* __restrict__ meta, const int* __restrict__ off_pad,
    float4* __restrict__ perm)
{
    __shared__ bf16x8 ldsS[512];   // 8KB, XOR-swizzled chunks
    __shared__ bf16x8 ldsQ[512];
    const int slot0 = blockIdx.x * 256;
    int r = 0;
    #pragma unroll
    for (int i = 1; i <= 8; ++i) r += (slot0 >= off_pad[i]);
    if (r >= 8) return;                       // past the end (block-uniform)

    const int t = threadIdx.x;
    for (int c = t; c < 512; c += 256) {      // stage W[r] swizzled
        const int row = c >> 3, c8 = c & 7, sw = c8 ^ (row & 7);
        ldsS[row * 8 + sw] = *reinterpret_cast<const bf16x8*>(WtS + (size_t)r * 4096 + c * 8);
        ldsQ[row * 8 + sw] = *reinterpret_cast<const bf16x8*>(WtQ + (size_t)r * 4096 + c * 8);
    }
    __syncthreads();

    const int lane = t & 63, l15 = lane & 15, g = lane >> 4, l7 = l15 & 7;
    const int sbase = slot0 + (t >> 6) * 64;

    int4 mt[4];
    #pragma unroll
    for (int b = 0; b < 4; ++b) mt[b] = meta[sbase + b * 16 + l15];

    bf16x8 xf[4][2], qf[4][2];                // 16 independent 16B gathers in flight
    #pragma unroll
    for (int b = 0; b < 4; ++b) {
        const unsigned short* xp = xS + (size_t)mt[b].x * 64;
        const unsigned short* qp = xQ + (size_t)mt[b].y * 64;
        xf[b][0] = *reinterpret_cast<const bf16x8*>(xp + g * 8);
        xf[b][1] = *reinterpret_cast<const bf16x8*>(xp + 32 + g * 8);
        qf[b][0] = *reinterpret_cast<const bf16x8*>(qp + g * 8);
        qf[b][1] = *reinterpret_cast<const bf16x8*>(qp + 32 + g * 8);
    }

    float p0[4] = {0.f, 0.f, 0.f, 0.f}, p1[4] = {0.f, 0.f, 0.f, 0.f};
    #pragma unroll
    for (int ot = 0; ot < 4; ++ot) {
        const int row8 = (ot * 16 + l15) * 8;
        const bf16x8 wS0 = ldsS[row8 + (g ^ l7)];
        const bf16x8 wS1 = ldsS[row8 + ((4 + g) ^ l7)];
        const bf16x8 wQ0 = ldsQ[row8 + (g ^ l7)];
        const bf16x8 wQ1 = ldsQ[row8 + ((4 + g) ^ l7)];
        const f32x4 bv = *reinterpret_cast<const f32x4*>(bSQ  + r * 64 + ot * 16 + g * 4);
        const f32x4 av = *reinterpret_cast<const f32x4*>(attn + r * 64 + ot * 16 + g * 4);
        #pragma unroll
        for (int b = 0; b < 4; ++b) {
            f32x4 acc = (f32x4){0.f, 0.f, 0.f, 0.f};
            acc = __builtin_amdgcn_mfma_f32_16x16x32_bf16(wS0, xf[b][0], acc, 0, 0, 0);
            acc = __builtin_amdgcn_mfma_f32_16x16x32_bf16(wS1, xf[b][1], acc, 0, 0, 0);
            acc = __builtin_amdgcn_mfma_f32_16x16x32_bf16(wQ0, qf[b][0], acc, 0, 0, 0);
            acc = __builtin_amdgcn_mfma_f32_16x16x32_bf16(wQ1, qf[b][1], acc, 0, 0, 0);
            float part = 0.f;
            #pragma unroll
            for (int j = 0; j < 4; ++j) {
                float v = acc[j] + bv[j];
                v = v > 0.f ? v : 0.2f * v;
                part += v * av[j];
            }
            if (ot < 2) p0[b] += part; else p1[b] += part;
        }
    }
    #pragma unroll
    for (int b = 0; b < 4; ++b) {
        p0[b] += __shfl_xor(p0[b], 16); p0[b] += __shfl_xor(p0[b], 32);
        p1[b] += __shfl_xor(p1[b], 16); p1[b] += __shfl_xor(p1[b], 32);
        if (g == 0 && mt[b].z >= 0)
            perm[mt[b].z] = make_float4(__int_as_float(mt[b].x), p0[b], p1[b], 0.f);
    }
}

// ---------- K4: per-node softmax + aggregation (bf16 feat gathers) ----------
__global__ __launch_bounds__(256) void aggregate_kernel(
    const unsigned short* __restrict__ xS, const int* __restrict__ offs,
    const float4* __restrict__ perm, float* __restrict__ out)
{
    __shared__ float2 ebuf[4][64];
    __shared__ int    sbuf[4][64];
    const int wv = threadIdx.x >> 6;
    const int n = blockIdx.x * 4 + wv;
    if (n >= NN) return;
    const int lane = threadIdx.x & 63;
    const int h2 = lane >> 5;        // which edge of the pair
    const int dp = lane & 31;        // d-pair: covers d = 2dp, 2dp+1
    const int s0 = offs[n], s1 = offs[n + 1];
    float a00 = 0.f, a01 = 0.f, a10 = 0.f, a11 = 0.f;   // [head][even/odd d]
    float d0s = 0.f, d1s = 0.f;
    if (s1 > s0) {
        float m0 = -1e30f, m1 = -1e30f;
        for (int j = s0 + lane; j < s1; j += 64) {
            const float4 p = perm[j];
            m0 = fmaxf(m0, p.y); m1 = fmaxf(m1, p.z);
        }
        #pragma unroll
        for (int m = 32; m; m >>= 1) {
            m0 = fmaxf(m0, __shfl_xor(m0, m));
            m1 = fmaxf(m1, __shfl_xor(m1, m));
        }
        for (int c = s0; c < s1; c += 64) {
            const int cnt = min(64, s1 - c);
            if (lane < cnt) {
                const float4 p = perm[c + lane];
                const float e0 = __expf(p.y - m0);
                const float e1 = __expf(p.z - m1);
                d0s += e0; d1s += e1;
                ebuf[wv][lane] = make_float2(e0, e1);
                sbuf[wv][lane] = (int)__float_as_uint(p.x);
            } else if (lane == cnt) {            // zero-weight pad for odd tails
                ebuf[wv][lane] = make_float2(0.f, 0.f);
                sbuf[wv][lane] = 0;
            }
            const int cp = cnt + (cnt & 1);
            #pragma unroll 4
            for (int k = 0; k < cp; k += 2) {
                const int ei = k + h2;
                const int sA = sbuf[wv][ei];
                const float2 w = ebuf[wv][ei];
                const unsigned fv = *reinterpret_cast<const unsigned*>(
                    xS + (size_t)sA * 64 + dp * 2);
                const float fx = bf2f((unsigned short)(fv & 0xFFFFu));
                const float fy = bf2f((unsigned short)(fv >> 16));
                a00 += fx * w.x; a01 += fy * w.x;
                a10 += fx * w.y; a11 += fy * w.y;
            }
        }
        #pragma unroll
        for (int m = 32; m; m >>= 1) {
            d0s += __shfl_xor(d0s, m);
            d1s += __shfl_xor(d1s, m);
        }
        a00 += __shfl_xor(a00, 32); a01 += __shfl_xor(a01, 32);
        a10 += __shfl_xor(a10, 32); a11 += __shfl_xor(a11, 32);
        const float r0 = 1.f / d0s, r1 = 1.f / d1s;
        a00 *= r0; a01 *= r0; a10 *= r1; a11 *= r1;
    }
    if (h2 == 0)
        *reinterpret_cast<float2*>(&out[(size_t)n * 128 + dp * 2])      = make_float2(a00, a01);
    else
        *reinterpret_cast<float2*>(&out[(size_t)n * 128 + 64 + dp * 2]) = make_float2(a10, a11);
}

// ---------- minimal-workspace fallback: direct logits + atomic scatter ----------
__global__ __launch_bounds__(256) void logits_direct_kernel(
    const float* __restrict__ feat, const float* __restrict__ nq,
    const int* __restrict__ src, const int* __restrict__ dst,
    const int* __restrict__ rt, const int* __restrict__ nid,
    const float* __restrict__ fc_src, const float* __restrict__ fc_src_b,
    const float* __restrict__ fc_qual, const float* __restrict__ fc_qual_b,
    const float* __restrict__ attn,
    float* __restrict__ e_buf, unsigned* __restrict__ emax)
{
    __shared__ float Ws[64][64];
    __shared__ float Wq[64][64];
    __shared__ float bl[64];
    __shared__ float al[64];
    const int r = blockIdx.y;
    const int t = threadIdx.x;
    for (int i = t; i < 4096; i += 256) {
        ((float*)Ws)[i] = fc_src[(size_t)r * 4096 + i];
        ((float*)Wq)[i] = fc_qual[(size_t)r * 4096 + i];
    }
    if (t < 64) {
        bl[t] = fc_src_b[r * 64 + t] + fc_qual_b[r * 64 + t];
        al[t] = attn[r * 64 + t];
    }
    __syncthreads();

    const int lane = t & 63;
    const int wid = blockIdx.x * 4 + (t >> 6);
    const int nw = gridDim.x * 4;
    for (int e = wid; e < NE; e += nw) {
        if (rt[e] != r) continue;
        const int s = src[e], q = nid[e];
        float fv = feat[(size_t)s * 64 + lane];
        float qv = nq[(size_t)q * 64 + lane];
        float acc = bl[lane];
        for (int k = 0; k < 64; ++k) {
            acc += __shfl(fv, k) * Ws[k][lane];
            acc += __shfl(qv, k) * Wq[k][lane];
        }
        acc = acc > 0.f ? acc : 0.2f * acc;
        float p = acc * al[lane];
        #pragma unroll
        for (int m = 1; m < 32; m <<= 1) p += __shfl_xor(p, m);
        if ((lane & 31) == 0) {
            int h = lane >> 5;
            e_buf[(size_t)e * 2 + h] = p;
            atomicMax(&emax[(size_t)dst[e] * 2 + h], fkey(p));
        }
    }
}

__global__ __launch_bounds__(256) void expdenom_kernel(
    const int* __restrict__ dst, float* __restrict__ e_buf,
    const unsigned* __restrict__ emax, float* __restrict__ denom)
{
    const int i = blockIdx.x * 256 + threadIdx.x;
    if (i >= NE * 2) return;
    const int e = i >> 1, h = i & 1;
    const int dn = dst[e];
    const float m = funkey(emax[(size_t)dn * 2 + h]);
    const float ex = __expf(e_buf[i] - m);
    e_buf[i] = ex;
    unsafeAtomicAdd(&denom[(size_t)dn * 2 + h], ex);
}

__global__ __launch_bounds__(256) void scatter_kernel(
    const float* __restrict__ feat, const int* __restrict__ src, const int* __restrict__ dst,
    const float* __restrict__ ex, const float* __restrict__ denom, float* __restrict__ out)
{
    const int e = blockIdx.x * 4 + (threadIdx.x >> 6);
    if (e >= NE) return;
    const int lane = threadIdx.x & 63;
    const int s = src[e], dn = dst[e];
    const float f = feat[(size_t)s * 64 + lane];
    const float a0 = ex[(size_t)e * 2]     / denom[(size_t)dn * 2];
    const float a1 = ex[(size_t)e * 2 + 1] / denom[(size_t)dn * 2 + 1];
    unsafeAtomicAdd(&out[(size_t)dn * 128 + lane],      f * a0);
    unsafeAtomicAdd(&out[(size_t)dn * 128 + 64 + lane], f * a1);
}

extern "C" void kernel_launch(void* const* d_in, const int* in_sizes, int n_in,
                              void* d_out, int out_size, void* d_ws, size_t ws_size,
                              hipStream_t stream)
{
    const float* feat      = (const float*)d_in[0];
    const int*   src       = (const int*)d_in[1];
    const int*   dst       = (const int*)d_in[2];
    const int*   rt        = (const int*)d_in[3];
    const int*   nid       = (const int*)d_in[4];
    const float* fc_src    = (const float*)d_in[5];
    const float* fc_src_b  = (const float*)d_in[6];
    const float* nq        = (const float*)d_in[7];
    const float* fc_qual   = (const float*)d_in[8];
    const float* fc_qual_b = (const float*)d_in[9];
    const float* attn      = (const float*)d_in[10];
    float* out = (float*)d_out;

    char* ws = (char*)d_ws;

    // ---- layout (~40 MB, no aliasing) ----
    int*    cnt      = (int*)ws;                            // NN       @0        (zeroed)
    int*    cnt_r    = (int*)(ws + 200000);                 // 8                  (zeroed)
    int*    cursor   = (int*)(ws + 262144);                 // NN (init by scan3)
    int*    offs     = (int*)(ws + 524288);                 // NN+1
    int*    partial  = (int*)(ws + 786432);                 // 256
    int*    off_pad  = (int*)(ws + 790528);                 // 9
    int*    rhist    = (int*)(ws + 802816);                 // 8*NBLK_E = 25000
    int*    rbase    = (int*)(ws + 905216);                 // 8*NBLK_E
    int4*   meta     = (int4*)(ws + 1048576);               // NE+2048 slots (12.83MB)
    float4* perm     = (float4*)(ws + 14000000);            // NE float4 (12.8MB)
    unsigned short* xS  = (unsigned short*)(ws + 26800000); // 6.4MB
    unsigned short* xQ  = (unsigned short*)(ws + 33200000); // 6.4MB
    unsigned short* WtS = (unsigned short*)(ws + 39600000); // 64KB
    unsigned short* WtQ = (unsigned short*)(ws + 39665536); // 64KB
    float*          bSQ = (float*)(ws + 39731072);          // 2KB
    const size_t need = 39733120;

    if (ws_size >= need) {
        hipMemsetAsync(ws, 0, 200064, stream);              // cnt + cnt_r

        prep_hist_kernel<<<6508, 256, 0, stream>>>(
            feat, nq, fc_src, fc_qual, fc_src_b, fc_qual_b, dst, rt,
            xS, xQ, WtS, WtQ, bSQ, cnt, cnt_r, rhist);

        const int nblk = (NN + 255) / 256;                  // 196
        scan1_kernel<<<nblk, 256, 0, stream>>>(cnt, offs, partial);
        scan2_kernel<<<1, 256, 0, stream>>>(partial, nblk, cnt_r, off_pad, meta);
        scan3_kernel<<<nblk, 256, 0, stream>>>(offs, partial, cursor);
        scanrb_kernel<<<8, 256, 0, stream>>>(rhist, off_pad, rbase);
        fillr_kernel<<<NBLK_E, 256, 0, stream>>>(
            rt, src, nid, dst, cursor, rbase, meta);

        logits_kernel<<<(NE + 8 * 256) / 256, 256, 0, stream>>>(
            xS, xQ, WtS, WtQ, bSQ, attn, meta, off_pad, perm);
        aggregate_kernel<<<(NN + 3) / 4, 256, 0, stream>>>(xS, offs, perm, out);
    } else {
        // minimal-workspace fallback (atomic path)
        float*    e_buf = (float*)ws;
        unsigned* emax  = (unsigned*)(ws + (size_t)NE * 2 * 4);
        float*    denom = (float*)(ws + (size_t)NE * 2 * 4 + (size_t)NN * 2 * 4);
        hipMemsetAsync(out, 0, (size_t)out_size * sizeof(float), stream);
        hipMemsetAsync(emax, 0, (size_t)NN * 2 * 4 * 2, stream);
        dim3 g(256, NR);
        logits_direct_kernel<<<g, 256, 0, stream>>>(
            feat, nq, src, dst, rt, nid, fc_src, fc_src_b, fc_qual, fc_qual_b,
            attn, e_buf, emax);
        expdenom_kernel<<<(NE * 2 + 255) / 256, 256, 0, stream>>>(dst, e_buf, emax, denom);
        scatter_kernel<<<(NE + 3) / 4, 256, 0, stream>>>(feat, src, dst, e_buf, denom, out);
    }
}